// Round 12
// baseline (811.153 us; speedup 1.0000x reference)
//
#include <hip/hip_runtime.h>

#define CNUM 1024
#define CDIM 256
#define EPS_CAND 6.0f

// out region offsets in FP32 elements (zbar, zsoft, zhard, symbols, phisoft)
#define OFF_ZBAR   ((size_t)0)
#define OFF_ZSOFT  ((size_t)16777216)
#define OFF_ZHARD  ((size_t)33554432)
#define OFF_SYM    ((size_t)50331648)
#define OFF_PHI    ((size_t)50397184)

typedef __attribute__((ext_vector_type(8))) short bf16x8;
typedef __attribute__((ext_vector_type(4))) float f32x4;

__device__ __forceinline__ unsigned short f2bf(float f){
  unsigned u = __float_as_uint(f);
  u += 0x7fffu + ((u >> 16) & 1u);
  return (unsigned short)(u >> 16);
}
__device__ __forceinline__ float bf2f(unsigned short h){
  return __uint_as_float(((unsigned)h) << 16);
}
__device__ __forceinline__ float clamp01(float v){ return fminf(1.0f, fmaxf(0.0f, v)); }
__device__ __forceinline__ float dot4(float4 a, float4 b){ return a.x*b.x + a.y*b.y + a.z*b.z + a.w*b.w; }

// LDS layout for k2's S tile: row t (2048 B), chunk (c>>3)^(t&7), halfword c&7
__device__ __forceinline__ int lbyte(int t, int c){
  return t*2048 + ((((c>>3) ^ (t&7)))<<4) + ((c&7)<<1);
}

// ---------- prep ----------
__global__ __launch_bounds__(256) void prep_convert(const float* __restrict__ centers,
                                                    unsigned short* __restrict__ cb16,
                                                    unsigned short* __restrict__ ct16){
  int gid = blockIdx.x*256 + threadIdx.x;
  int c = gid >> 6, d0 = (gid & 63)*4;
  float4 v = *reinterpret_cast<const float4*>(centers + (size_t)c*CDIM + d0);
  unsigned short b0=f2bf(v.x), b1=f2bf(v.y), b2=f2bf(v.z), b3=f2bf(v.w);
  unsigned lo = (unsigned)b0 | ((unsigned)b1<<16);
  unsigned hi = (unsigned)b2 | ((unsigned)b3<<16);
  *reinterpret_cast<uint2*>(cb16 + (size_t)c*CDIM + d0) = make_uint2(lo, hi);
  ct16[(size_t)(d0+0)*CNUM + c] = b0;
  ct16[(size_t)(d0+1)*CNUM + c] = b1;
  ct16[(size_t)(d0+2)*CNUM + c] = b2;
  ct16[(size_t)(d0+3)*CNUM + c] = b3;
}

__global__ __launch_bounds__(256) void prep_e2(const float* __restrict__ centers, float* __restrict__ e2){
  int k = blockIdx.x*256 + threadIdx.x;
  const float4* c4 = reinterpret_cast<const float4*>(centers) + (size_t)k*(CDIM/4);
  float s = 0.f;
  #pragma unroll
  for (int i=0;i<CDIM/4;i++){ float4 v = c4[i]; s += dot4(v,v); }
  e2[k] = s;
}

// ---------- K1: GEMM1 + x2 -> full sq bf16, blocked [tb32][c][t32] ----------
__global__ __launch_bounds__(512) void k1_gemm1(const float* __restrict__ data,
                                                const unsigned short* __restrict__ cb16,
                                                const float* __restrict__ e2g,
                                                unsigned short* __restrict__ scr){
  __shared__ unsigned short xb[64*256];
  __shared__ unsigned short cb[64*256];
  __shared__ float e2s[64];
  __shared__ float px[8*64];
  __shared__ float x2s[64];

  const int tid = threadIdx.x;
  const int w = tid>>6, lane = tid&63;
  const int l15 = lane&15, g = lane>>4;
  const int sb = (blockIdx.x & 7)*128 + (blockIdx.x >> 3);
  const int b = sb>>4, hw0 = (sb&15)*64;

  // stage x (bf16, swizzled) + per-(wave,dim-range) x2 partial
  {
    float p2 = 0.f;
    const float* dp = data + ((size_t)b*CDIM + 32*w)*1024 + hw0 + lane;
    #pragma unroll
    for (int i=0;i<16;i++){
      int dd = 2*i;
      float v0 = dp[(size_t)dd*1024];
      float v1 = dp[(size_t)(dd+1)*1024];
      p2 += v0*v0 + v1*v1;
      unsigned pk = (unsigned)f2bf(v0) | ((unsigned)f2bf(v1)<<16);
      int d = 32*w + dd;
      int s = d>>3;
      *reinterpret_cast<unsigned*>((char*)xb + lane*512 + (((s ^ (lane&7))<<4)) + (d&7)*2) = pk;
    }
    px[w*64 + lane] = p2;
  }

  const int tt  = w & 3;
  const int ch2 = w >> 2;
  const int t   = 16*tt + l15;
  const int t32 = 16*(tt&1) + l15;
  const size_t tb = ((size_t)b*1024 + hw0)/32 + (tt>>1);

  for (int cc=0; cc<16; cc++){
    __syncthreads();
    #pragma unroll
    for (int it=0; it<4; it++){
      int e = tid + 512*it;
      int c = e>>5, s = e&31;
      uint4 v = *reinterpret_cast<const uint4*>(cb16 + ((size_t)(cc*64 + c))*CDIM + s*8);
      *reinterpret_cast<uint4*>((char*)cb + c*512 + ((s ^ (c&7))<<4)) = v;
    }
    if (tid < 64) e2s[tid] = e2g[cc*64 + tid];
    if (cc == 0 && tid >= 64 && tid < 128){
      int tt2 = tid - 64;
      float s = 0.f;
      #pragma unroll
      for (int wv=0; wv<8; wv++) s += px[wv*64 + tt2];
      x2s[tt2] = s;
    }
    __syncthreads();

    f32x4 acc0 = {0.f,0.f,0.f,0.f}, acc1 = {0.f,0.f,0.f,0.f};
    const int c0 = 32*ch2 + l15, c1 = c0 + 16;
    #pragma unroll
    for (int k=0;k<8;k++){
      bf16x8 bf = *reinterpret_cast<const bf16x8*>((const char*)xb + t*512 + (((4*k+g) ^ (t&7))<<4));
      bf16x8 a0 = *reinterpret_cast<const bf16x8*>((const char*)cb + c0*512 + (((4*k+g) ^ (c0&7))<<4));
      bf16x8 a1 = *reinterpret_cast<const bf16x8*>((const char*)cb + c1*512 + (((4*k+g) ^ (c1&7))<<4));
      acc0 = __builtin_amdgcn_mfma_f32_16x16x32_bf16(a0, bf, acc0, 0,0,0);
      acc1 = __builtin_amdgcn_mfma_f32_16x16x32_bf16(a1, bf, acc1, 0,0,0);
    }
    float x2v = x2s[t];
    #pragma unroll
    for (int r=0;r<4;r++){
      int cr0 = 32*ch2 + 4*g + r;
      int cr1 = cr0 + 16;
      scr[tb*32768 + (size_t)(cc*64 + cr0)*32 + t32] = f2bf(x2v - 2.0f*acc0[r] + e2s[cr0]);
      scr[tb*32768 + (size_t)(cc*64 + cr1)*32 + t32] = f2bf(x2v - 2.0f*acc1[r] + e2s[cr1]);
    }
  }
}

// ---------- K2: softmax + exact argmin + phi/sym/zbar(+zhard,+GEMM2 zsoft in WS mode) ----------
template<bool WS>
__global__ __launch_bounds__(512, 6) void k2_soft(const float* __restrict__ data,
                                                  const float* __restrict__ centers,
                                                  const unsigned short* __restrict__ ct16,
                                                  const unsigned short* __restrict__ scr,
                                                  float* __restrict__ out){
  __shared__ unsigned short S[16*1024];   // 32 KB: sq bf16 -> phi bf16, lbyte layout
  __shared__ unsigned short H[16*256];    //  8 KB: hard bf16 -> zsoft bf16

  const int tid = threadIdx.x;
  const int w = tid>>6, lane = tid&63;
  const int l15 = lane&15, g = lane>>4;
  const int sb = (blockIdx.x & 7)*512 + (blockIdx.x >> 3);
  const int tok0 = sb*16;
  const int bb = tok0>>10, hw0 = tok0&1023;
  const size_t tb = (size_t)(tok0>>5);
  const int h16 = (tok0>>4)&1;

  // ---- P0: stream sq16 slice -> LDS (transpose scatter) ----
  #pragma unroll
  for (int it=0; it<4; it++){
    int e = tid + 512*it;            // 0..2047: c = e>>1, q = e&1
    int c = e>>1, q = e&1;
    uint4 v = *reinterpret_cast<const uint4*>(scr + tb*32768 + (size_t)c*32 + 16*h16 + 8*q);
    const unsigned short* p = (const unsigned short*)&v;
    #pragma unroll
    for (int u=0;u<8;u++){
      int t = 8*q + u;
      *(unsigned short*)((char*)S + lbyte(t, c)) = p[u];
    }
  }
  __syncthreads();

  // ---- P1: per-token softmax + fp64 refine ----
  {
    const int t = tid>>5;
    const int j = tid&31;
    const int hb = (lane>=32)?32:0;
    const int rot = (j>>3)&3;
    float a[32];
    #pragma unroll
    for (int qi=0;qi<4;qi++){
      int qq = (qi + rot)&3;
      int chunk = (4*j + qq) ^ (t&7);
      uint4 v = *reinterpret_cast<const uint4*>((const char*)S + t*2048 + chunk*16);
      const unsigned short* p = (const unsigned short*)&v;
      #pragma unroll
      for (int u=0;u<8;u++) a[8*qq+u] = bf2f(p[u]);
    }
    float mns = 3.4e38f;
    #pragma unroll
    for (int i=0;i<32;i++) mns = fminf(mns, a[i]);
    #pragma unroll
    for (int m=16;m>=1;m>>=1) mns = fminf(mns, __shfl_xor(mns, m));
    float thr = mns + EPS_CAND;
    unsigned cm = 0;
    #pragma unroll
    for (int i=0;i<32;i++) if (a[i] < thr) cm |= (1u<<i);

    double bestd = 1.0e300; int bestk = CNUM;
    const float* xp = data + (size_t)bb*262144 + hw0 + t;
    for(;;){
      unsigned long long bal = __ballot(cm != 0);
      unsigned half = (lane<32)? (unsigned)(bal & 0xffffffffULL) : (unsigned)(bal>>32);
      if (!half) break;
      int src = __ffs(half)-1;
      unsigned cmsrc = (unsigned)__shfl((int)cm, hb + src);
      int ii = __ffs(cmsrc)-1;
      int k = 32*src + ii;                 // lane src owns centers 32*src..+32
      if (j==src) cm &= ~(1u<<ii);
      double acc = 0.0;
      const float* crow = centers + (size_t)k*CDIM;
      #pragma unroll
      for (int q2=0;q2<8;q2++){
        double xv = (double)xp[(size_t)(j+32*q2)*1024];
        double ev = (double)crow[j+32*q2];
        double df = xv-ev; acc = fma(df,df,acc);
      }
      #pragma unroll
      for (int m=16;m>=1;m>>=1) acc += __shfl_xor(acc, m);
      if (acc < bestd || (acc==bestd && k<bestk)){ bestd=acc; bestk=k; }
    }
    if (j==0) out[OFF_SYM + tok0 + t] = (float)bestk;

    float dmn = sqrtf(fmaxf(mns, 0.f));
    float sum = 0.f;
    #pragma unroll
    for (int i=0;i<32;i++){
      float d = sqrtf(fmaxf(a[i], 0.f));
      a[i] = __expf(dmn - d);
      sum += a[i];
    }
    #pragma unroll
    for (int m=16;m>=1;m>>=1) sum += __shfl_xor(sum, m);
    float rs = 1.f/sum;
    #pragma unroll
    for (int qi=0;qi<4;qi++){
      int qq = (qi + rot)&3;
      int chunk = (4*j + qq) ^ (t&7);
      unsigned w0=0,w1=0,w2=0,w3=0;
      unsigned short h0,h1;
      h0 = f2bf(clamp01(a[8*qq+0]*rs)); h1 = f2bf(clamp01(a[8*qq+1]*rs)); w0 = (unsigned)h0 | ((unsigned)h1<<16);
      h0 = f2bf(clamp01(a[8*qq+2]*rs)); h1 = f2bf(clamp01(a[8*qq+3]*rs)); w1 = (unsigned)h0 | ((unsigned)h1<<16);
      h0 = f2bf(clamp01(a[8*qq+4]*rs)); h1 = f2bf(clamp01(a[8*qq+5]*rs)); w2 = (unsigned)h0 | ((unsigned)h1<<16);
      h0 = f2bf(clamp01(a[8*qq+6]*rs)); h1 = f2bf(clamp01(a[8*qq+7]*rs)); w3 = (unsigned)h0 | ((unsigned)h1<<16);
      *reinterpret_cast<uint4*>((char*)S + t*2048 + chunk*16) = make_uint4(w0,w1,w2,w3);
    }
    const float* hrow = centers + (size_t)bestk*CDIM;
    #pragma unroll
    for (int q2=0;q2<8;q2++){
      int c = j + 32*q2;
      *(unsigned short*)((char*)H + t*512 + ((2*c) ^ ((t&7)<<4))) = f2bf(hrow[c]);
    }
  }
  __syncthreads();

  // ---- P2a: phi fp32 store ----
  #pragma unroll
  for (int it=0; it<8; ++it){
    int e = tid + 512*it;              // 0..4095: c = e>>2, q = e&3
    int c = e>>2, q = e&3;
    float4 v; float* vp = (float*)&v;
    #pragma unroll
    for (int u=0;u<4;u++){
      int t = 4*q + u;
      vp[u] = bf2f(*(const unsigned short*)((const char*)S + lbyte(t, c)));
    }
    *reinterpret_cast<float4*>(out + OFF_PHI + (size_t)bb*1048576 + (size_t)c*1024 + hw0 + 4*q) = v;
  }
  // ---- P2b: zbar (+zhard in WS mode) ----
  #pragma unroll
  for (int it=0; it<2; ++it){
    int e = tid + 512*it;              // 0..1023: d = e>>2, q = e&3
    int d = e>>2, q = e&3;
    float4 v; float* vp = (float*)&v;
    #pragma unroll
    for (int u=0;u<4;u++){
      int t = 4*q + u;
      vp[u] = bf2f(*(const unsigned short*)((const char*)H + t*512 + ((2*d) ^ ((t&7)<<4))));
    }
    size_t base = (size_t)bb*262144 + (size_t)d*1024 + hw0 + 4*q;
    *reinterpret_cast<float4*>(out + OFF_ZBAR + base) = v;
    if (WS) *reinterpret_cast<float4*>(out + OFF_ZHARD + base) = v;
  }

  if (WS){
    __syncthreads();
    // ---- P3: GEMM2 from LDS phi16; A = ct16 d-rows ----
    f32x4 z0 = {0.f,0.f,0.f,0.f}, z1 = {0.f,0.f,0.f,0.f};
    const unsigned short* ar0 = ct16 + (size_t)(16*w + l15)*CNUM;
    const unsigned short* ar1 = ct16 + (size_t)(16*(w+8) + l15)*CNUM;
    #pragma unroll 8
    for (int ks=0; ks<32; ks++){
      int chunk = (4*ks + g) ^ (l15 & 7);
      bf16x8 bfrag = *reinterpret_cast<const bf16x8*>((const char*)S + l15*2048 + chunk*16);
      bf16x8 a0 = *reinterpret_cast<const bf16x8*>(ar0 + 32*ks + 8*g);
      bf16x8 a1 = *reinterpret_cast<const bf16x8*>(ar1 + 32*ks + 8*g);
      z0 = __builtin_amdgcn_mfma_f32_16x16x32_bf16(a0, bfrag, z0, 0,0,0);
      z1 = __builtin_amdgcn_mfma_f32_16x16x32_bf16(a1, bfrag, z1, 0,0,0);
    }
    // stage acc -> H (t = l15, d = 16*mt + 4g + r)
    #pragma unroll
    for (int mi=0;mi<2;mi++){
      f32x4 ac = mi ? z1 : z0;
      int mt = w + 8*mi;
      int d0 = 16*mt + 4*g;
      unsigned short h0,h1;
      unsigned w0,w1;
      h0 = f2bf(ac[0]); h1 = f2bf(ac[1]); w0 = (unsigned)h0 | ((unsigned)h1<<16);
      h0 = f2bf(ac[2]); h1 = f2bf(ac[3]); w1 = (unsigned)h0 | ((unsigned)h1<<16);
      *reinterpret_cast<uint2*>((char*)H + l15*512 + ((2*d0) ^ ((l15&7)<<4))) = make_uint2(w0,w1);
    }
    __syncthreads();
    // ---- P4: zsoft store ----
    #pragma unroll
    for (int it=0; it<2; ++it){
      int e = tid + 512*it;
      int d = e>>2, q = e&3;
      float4 v; float* vp = (float*)&v;
      #pragma unroll
      for (int u=0;u<4;u++){
        int t = 4*q + u;
        vp[u] = bf2f(*(const unsigned short*)((const char*)H + t*512 + ((2*d) ^ ((t&7)<<4))));
      }
      *reinterpret_cast<float4*>(out + OFF_ZSOFT + (size_t)bb*262144 + (size_t)d*1024 + hw0 + 4*q) = v;
    }
  }
}

// ---------- K3 (fallback only): GEMM2 from phi fp32 -> zsoft, + zhard gather ----------
__global__ __launch_bounds__(512) void k3_fb(const float* __restrict__ phi,
                                             const float* __restrict__ centers,
                                             const unsigned short* __restrict__ ct16,
                                             const float* __restrict__ symf,
                                             float* __restrict__ out){
  __shared__ unsigned short pls[64*64];   // 8 KB
  __shared__ unsigned short hr[64*256];   // 32 KB
  const int tid = threadIdx.x;
  const int w = tid>>6, lane = tid&63;
  const int l15 = lane&15, g = lane>>4;
  const int sb = (blockIdx.x & 7)*128 + (blockIdx.x >> 3);
  const int b = sb>>4, hw0 = (sb&15)*64;
  const size_t tok0g = (size_t)b*1024 + hw0;

  // stage hard rows (wave w: rows 8w..8w+8)
  #pragma unroll
  for (int r2=0;r2<8;r2++){
    int r = 8*w + r2;
    int sym = (int)symf[tok0g + r];
    sym = (sym < 0) ? 0 : (sym > 1023 ? 1023 : sym);
    const float* crow = centers + (size_t)sym*CDIM;
    #pragma unroll
    for (int i=0;i<4;i++){
      int c = lane + 64*i;
      *(unsigned short*)((char*)hr + r*512 + ((2*c) ^ ((r&7)<<4))) = f2bf(crow[c]);
    }
  }

  f32x4 acc[2][4];
  #pragma unroll
  for (int h=0;h<2;h++)
    #pragma unroll
    for (int t2=0;t2<4;t2++) acc[h][t2] = (f32x4){0.f,0.f,0.f,0.f};

  for (int ks=0; ks<16; ks++){
    int k0s = ks*64;
    __syncthreads();
    #pragma unroll
    for (int it=0; it<4; it++){
      int e = tid + 512*it;
      int kp = e>>6, t = e&63;
      const float* pp = phi + (size_t)b*1048576 + (size_t)(k0s + 2*kp)*1024 + hw0 + t;
      float v0 = pp[0];
      float v1 = pp[1024];
      unsigned pk = (unsigned)f2bf(v0) | ((unsigned)f2bf(v1)<<16);
      int kk = 2*kp;
      int s = kk>>3;
      *reinterpret_cast<unsigned*>((char*)pls + t*128 + ((s ^ (t&7))<<4) + (kk&7)*2) = pk;
    }
    __syncthreads();
    #pragma unroll
    for (int ki=0; ki<2; ki++){
      int kk0 = k0s + 32*ki;
      bf16x8 a0 = *reinterpret_cast<const bf16x8*>(ct16 + (size_t)(32*w + l15)*CNUM + kk0 + 8*g);
      bf16x8 a1 = *reinterpret_cast<const bf16x8*>(ct16 + (size_t)(32*w + 16 + l15)*CNUM + kk0 + 8*g);
      #pragma unroll
      for (int t2=0;t2<4;t2++){
        int t = 16*t2 + l15;
        bf16x8 bf = *reinterpret_cast<const bf16x8*>((const char*)pls + t*128 + (((4*ki+g) ^ (t&7))<<4));
        acc[0][t2] = __builtin_amdgcn_mfma_f32_16x16x32_bf16(a0, bf, acc[0][t2], 0,0,0);
        acc[1][t2] = __builtin_amdgcn_mfma_f32_16x16x32_bf16(a1, bf, acc[1][t2], 0,0,0);
      }
    }
  }
  #pragma unroll
  for (int h=0;h<2;h++)
    #pragma unroll
    for (int t2=0;t2<4;t2++)
      #pragma unroll
      for (int r=0;r<4;r++){
        int d = 32*w + 16*h + 4*g + r;
        out[OFF_ZSOFT + (size_t)b*262144 + (size_t)d*1024 + hw0 + 16*t2 + l15] = acc[h][t2][r];
      }
  __syncthreads();
  // zhard transposed store from hr
  #pragma unroll
  for (int it=0; it<8; ++it){
    int e = tid + 512*it;              // 0..4095: d = e>>4, q = e&15
    int d = e>>4, q = e&15;
    float4 v; float* vp = (float*)&v;
    #pragma unroll
    for (int u=0;u<4;u++){
      int t = 4*q + u;
      vp[u] = bf2f(*(const unsigned short*)((const char*)hr + t*512 + ((2*d) ^ ((t&7)<<4))));
    }
    *reinterpret_cast<float4*>(out + OFF_ZHARD + (size_t)b*262144 + (size_t)d*1024 + hw0 + 4*q) = v;
  }
}

extern "C" void kernel_launch(void* const* d_in, const int* in_sizes, int n_in,
                              void* d_out, int out_size, void* d_ws, size_t ws_size,
                              hipStream_t stream) {
  const float* data    = (const float*)d_in[0];
  const float* centers = (const float*)d_in[1];
  float* out           = (float*)d_out;

  const size_t SQ_BYTES = (size_t)65536*1024*2;  // 134 MB
  bool wsmode = (ws_size >= SQ_BYTES + 1048576 + 4096);

  unsigned short* cb16;
  unsigned short* ct16;
  float* e2;
  unsigned short* scr;
  if (wsmode){
    scr  = (unsigned short*)d_ws;
    cb16 = (unsigned short*)((char*)d_ws + SQ_BYTES);
    ct16 = (unsigned short*)((char*)d_ws + SQ_BYTES + 524288);
    e2   = (float*)((char*)d_ws + SQ_BYTES + 1048576);
  } else {
    scr  = (unsigned short*)(out + OFF_ZSOFT);    // zsoft+zhard as scratch
    cb16 = (unsigned short*)d_ws;
    ct16 = (unsigned short*)((char*)d_ws + 524288);
    e2   = (float*)((char*)d_ws + 1048576);
  }

  prep_convert<<<dim3(256), dim3(256), 0, stream>>>(centers, cb16, ct16);
  prep_e2<<<dim3(4), dim3(256), 0, stream>>>(centers, e2);
  k1_gemm1<<<dim3(1024), dim3(512), 0, stream>>>(data, cb16, e2, scr);
  if (wsmode){
    k2_soft<true><<<dim3(4096), dim3(512), 0, stream>>>(data, centers, ct16, scr, out);
  } else {
    k2_soft<false><<<dim3(4096), dim3(512), 0, stream>>>(data, centers, ct16, scr, out);
    k3_fb<<<dim3(1024), dim3(512), 0, stream>>>(out + OFF_PHI, centers, ct16, out + OFF_SYM, out);
  }
}